// Round 6
// baseline (258.724 us; speedup 1.0000x reference)
//
#include <hip/hip_runtime.h>
#include <math.h>

// MLA decode attention (fp32), flash-decoding split over sequence chunks.
// B=64, H=16, latent D=576, V=512, MAX_LEN=4096.
//
// R5: R2 structure (best: 224us) + row-pair software pipelining.
//  - Cycle model from R2's 224us: per-row serial chain ~700-800cy =
//    LDS-load latency (~230) + serial 36-FMA dot (144) + 4 DEPENDENT
//    __shfl_xor (~300-400) + softmax. Throughput floors are all <50us.
//    R3 (LDS-inst halving) and R4 (dbuf staging) attacked non-binding
//    constraints and paid occupancy for it -> both regressed.
//  - Fix: process rows in PAIRS. 18 ds_read issued together; dot split
//    into 2 partials per row (4 independent 18-deep FMA chains); the two
//    butterflies are independent shfl chains the scheduler interleaves;
//    ONE paired defer-max check; PV fused acc += p0*x0 + p1*x1.
//  - Keeps R2: wave owns 4 heads (no cross-wave merge), dd-16 lane slice,
//    single 36.9KB LDS tile, in-LDS newpos overwrite, per-lane m/l.
//  - ~160 VGPR -> 3 waves/SIMD, 3 blocks/CU (12 waves/CU).

namespace {
constexpr int NH = 16;
constexpr int MAXLEN = 4096;
constexpr int D = 576;
constexpr int DV = 512;
constexpr int TR = 16;        // tile rows; LDS tile = TR*D*4 = 36864 B
constexpr float SCALE_LOG2E = 0.041666666666666664f * 1.4426950408889634f;
constexpr float NEGINF = -1e30f;
constexpr float THR2 = 8.0f;  // defer-max threshold (log2 domain)
}

__device__ __forceinline__ void gload_lds16(const void* g, void* l) {
    __builtin_amdgcn_global_load_lds(
        (const __attribute__((address_space(1))) void*)g,
        (__attribute__((address_space(3))) void*)l, 16, 0, 0);
}

__global__ __launch_bounds__(256)
void mla_chunk(const float* __restrict__ qg,
               const float* __restrict__ kvnew,
               const float* __restrict__ cache,
               const int* __restrict__ lens,
               float* __restrict__ ws_o,
               float* __restrict__ ws_ml,
               int nchunk, int chunk)
{
    const int c = blockIdx.x;
    const int b = blockIdx.y;
    const int tid = (int)threadIdx.x;

    const int total = lens[b] + 1;
    const int start = c * chunk;
    if (start >= total) return;          // uniform early-exit before barriers
    const int end = min(start + chunk, total);
    const int newpos = total - 1;

    __shared__ float kv_s[TR][D];        // 36864 B

    const int wave = tid >> 6;
    const int lane = tid & 63;
    const int hl = lane >> 4;            // head within wave's group of 4
    const int dd = lane & 15;            // d-slice
    const int head = wave * 4 + hl;

    // Q into registers (scale pre-folded, log2 domain)
    float4 q[9];
    {
        const float* qp = qg + ((size_t)b * NH + head) * D + dd * 4;
        #pragma unroll
        for (int j = 0; j < 9; ++j) {
            float4 v = *(const float4*)(qp + j * 64);
            v.x *= SCALE_LOG2E; v.y *= SCALE_LOG2E;
            v.z *= SCALE_LOG2E; v.w *= SCALE_LOG2E;
            q[j] = v;
        }
    }

    float4 acc[8];
    #pragma unroll
    for (int j = 0; j < 8; ++j) acc[j] = make_float4(0.f, 0.f, 0.f, 0.f);
    float m2 = NEGINF, l = 0.f;

    for (int r0 = start; r0 < end; r0 += TR) {
        const int nrows = min(TR, end - r0);
        // ---- stage 16 rows -> LDS ----
        {
            const char* src = (const char*)(cache + ((size_t)b * MAXLEN + r0) * D);
            char* dst = (char*)&kv_s[0][0];
            const int o = tid * 16;
            #pragma unroll
            for (int it = 0; it < 9; ++it)
                gload_lds16(src + it * 4096 + o, dst + it * 4096 + o);
        }
        __syncthreads();
        if (newpos >= r0 && newpos < r0 + TR) {   // block-uniform, rare
            if (tid < D / 4)
                ((float4*)&kv_s[newpos - r0][0])[tid] =
                    ((const float4*)(kvnew + (size_t)b * D))[tid];
            __syncthreads();
        }

        // ---- row pairs: pipelined score + softmax + PV, no barriers ----
        int r = 0;
        for (; r + 2 <= nrows; r += 2) {
            const float* k0 = &kv_s[r][0] + dd * 4;
            const float* k1 = &kv_s[r + 1][0] + dd * 4;
            float4 x0[9], x1[9];
            #pragma unroll
            for (int j = 0; j < 9; ++j) x0[j] = *(const float4*)(k0 + j * 64);
            #pragma unroll
            for (int j = 0; j < 9; ++j) x1[j] = *(const float4*)(k1 + j * 64);

            float s0a = 0.f, s0b = 0.f, s1a = 0.f, s1b = 0.f;
            #pragma unroll
            for (int j = 0; j < 9; ++j) {
                if (j & 1) {
                    s0b = fmaf(x0[j].x, q[j].x, s0b);
                    s0b = fmaf(x0[j].y, q[j].y, s0b);
                    s0b = fmaf(x0[j].z, q[j].z, s0b);
                    s0b = fmaf(x0[j].w, q[j].w, s0b);
                    s1b = fmaf(x1[j].x, q[j].x, s1b);
                    s1b = fmaf(x1[j].y, q[j].y, s1b);
                    s1b = fmaf(x1[j].z, q[j].z, s1b);
                    s1b = fmaf(x1[j].w, q[j].w, s1b);
                } else {
                    s0a = fmaf(x0[j].x, q[j].x, s0a);
                    s0a = fmaf(x0[j].y, q[j].y, s0a);
                    s0a = fmaf(x0[j].z, q[j].z, s0a);
                    s0a = fmaf(x0[j].w, q[j].w, s0a);
                    s1a = fmaf(x1[j].x, q[j].x, s1a);
                    s1a = fmaf(x1[j].y, q[j].y, s1a);
                    s1a = fmaf(x1[j].z, q[j].z, s1a);
                    s1a = fmaf(x1[j].w, q[j].w, s1a);
                }
            }
            float s0 = s0a + s0b;
            float s1 = s1a + s1b;
            #pragma unroll
            for (int m = 1; m <= 8; m <<= 1) {   // two independent chains
                s0 += __shfl_xor(s0, m);
                s1 += __shfl_xor(s1, m);
            }

            // paired defer-max online softmax
            const float smax = fmaxf(s0, s1);
            if (smax > m2 + THR2) {              // rare rescale
                const float scl = exp2f(m2 - smax);
                m2 = smax; l *= scl;
                #pragma unroll
                for (int j = 0; j < 8; ++j) {
                    acc[j].x *= scl; acc[j].y *= scl;
                    acc[j].z *= scl; acc[j].w *= scl;
                }
            }
            const float p0 = exp2f(s0 - m2);     // bounded by 2^THR2
            const float p1 = exp2f(s1 - m2);
            l += p0 + p1;
            #pragma unroll
            for (int j = 0; j < 8; ++j) {
                acc[j].x = fmaf(p1, x1[j].x, fmaf(p0, x0[j].x, acc[j].x));
                acc[j].y = fmaf(p1, x1[j].y, fmaf(p0, x0[j].y, acc[j].y));
                acc[j].z = fmaf(p1, x1[j].z, fmaf(p0, x0[j].z, acc[j].z));
                acc[j].w = fmaf(p1, x1[j].w, fmaf(p0, x0[j].w, acc[j].w));
            }
        }
        if (r < nrows) {                         // odd tail row
            const float* k0 = &kv_s[r][0] + dd * 4;
            float4 x0[9];
            #pragma unroll
            for (int j = 0; j < 9; ++j) x0[j] = *(const float4*)(k0 + j * 64);
            float sa = 0.f, sb = 0.f;
            #pragma unroll
            for (int j = 0; j < 9; ++j) {
                if (j & 1) {
                    sb = fmaf(x0[j].x, q[j].x, sb);
                    sb = fmaf(x0[j].y, q[j].y, sb);
                    sb = fmaf(x0[j].z, q[j].z, sb);
                    sb = fmaf(x0[j].w, q[j].w, sb);
                } else {
                    sa = fmaf(x0[j].x, q[j].x, sa);
                    sa = fmaf(x0[j].y, q[j].y, sa);
                    sa = fmaf(x0[j].z, q[j].z, sa);
                    sa = fmaf(x0[j].w, q[j].w, sa);
                }
            }
            float s0 = sa + sb;
            #pragma unroll
            for (int m = 1; m <= 8; m <<= 1) s0 += __shfl_xor(s0, m);
            if (s0 > m2 + THR2) {
                const float scl = exp2f(m2 - s0);
                m2 = s0; l *= scl;
                #pragma unroll
                for (int j = 0; j < 8; ++j) {
                    acc[j].x *= scl; acc[j].y *= scl;
                    acc[j].z *= scl; acc[j].w *= scl;
                }
            }
            const float p0 = exp2f(s0 - m2);
            l += p0;
            #pragma unroll
            for (int j = 0; j < 8; ++j) {
                acc[j].x = fmaf(p0, x0[j].x, acc[j].x);
                acc[j].y = fmaf(p0, x0[j].y, acc[j].y);
                acc[j].z = fmaf(p0, x0[j].z, acc[j].z);
                acc[j].w = fmaf(p0, x0[j].w, acc[j].w);
            }
        }
        __syncthreads();                 // protect kv_s before next stage
    }

    // ---- write partials: lane owns dims {j*64+dd*4..+3} of its head ----
    float* op = ws_o + (((size_t)b * nchunk + c) * NH + head) * DV + dd * 4;
    #pragma unroll
    for (int j = 0; j < 8; ++j)
        *(float4*)(op + j * 64) = acc[j];
    if (dd == 0) {
        const size_t mlb = (((size_t)b * nchunk + c) * NH + head) * 2;
        ws_ml[mlb]     = m2;             // log2-domain running max
        ws_ml[mlb + 1] = l;
    }
}

__global__ __launch_bounds__(256)
void mla_reduce(const int* __restrict__ lens,
                const float* __restrict__ ws_o,
                const float* __restrict__ ws_ml,
                float* __restrict__ out,
                int nchunk, int chunk)
{
    const int h = blockIdx.x;
    const int b = blockIdx.y;
    const int tid = (int)threadIdx.x;
    const int total = lens[b] + 1;
    const int nact = min(nchunk, (total + chunk - 1) / chunk);

    float M = NEGINF;
    for (int c = 0; c < nact; ++c)
        M = fmaxf(M, ws_ml[(((size_t)b * nchunk + c) * NH + h) * 2]);

    float a0 = 0.f, a1 = 0.f, L = 0.f;
    for (int c = 0; c < nact; ++c) {
        const size_t mlb = (((size_t)b * nchunk + c) * NH + h) * 2;
        const float w = exp2f(ws_ml[mlb] - M);   // log2-domain merge
        L += w * ws_ml[mlb + 1];
        const float2 o = *(const float2*)&ws_o[
            (((size_t)b * nchunk + c) * NH + h) * (size_t)DV + 2 * tid];
        a0 = fmaf(w, o.x, a0);
        a1 = fmaf(w, o.y, a1);
    }
    const float inv = 1.f / L;
    *(float2*)&out[((size_t)b * NH + h) * (size_t)DV + 2 * tid] =
        make_float2(a0 * inv, a1 * inv);
}

extern "C" void kernel_launch(void* const* d_in, const int* in_sizes, int n_in,
                              void* d_out, int out_size, void* d_ws, size_t ws_size,
                              hipStream_t stream)
{
    (void)in_sizes; (void)n_in; (void)out_size;
    const float* qg    = (const float*)d_in[0];   // [B,H,576]
    const float* kvnew = (const float*)d_in[1];   // [B,1,576]
    const float* cache = (const float*)d_in[2];   // [B,4096,576]
    const int*   lens  = (const int*)d_in[3];     // [B]
    float* out = (float*)d_out;                   // [B,H,512] fp32
    const int NB = 64;

    // largest chunk split that fits the workspace (67 MB at nchunk=32)
    int nchunk = 32;
    while (nchunk > 1 &&
           (size_t)NB * nchunk * NH * (DV + 2) * sizeof(float) > ws_size)
        nchunk >>= 1;
    const int chunk = MAXLEN / nchunk;

    float* ws_o  = (float*)d_ws;
    float* ws_ml = ws_o + (size_t)NB * nchunk * NH * DV;

    dim3 gA(nchunk, NB);
    mla_chunk<<<gA, 256, 0, stream>>>(qg, kvnew, cache, lens, ws_o, ws_ml,
                                      nchunk, chunk);
    dim3 gB(NH, NB);
    mla_reduce<<<gB, 256, 0, stream>>>(lens, ws_o, ws_ml, out, nchunk, chunk);
}